// Round 1
// baseline (127.654 us; speedup 1.0000x reference)
//
#include <hip/hip_runtime.h>
#include <math.h>

// TransE scoring: out[b,e] = sigmoid(GAMMA - sum_d |(ent_w[sub[b]]+rel_w[rel[b]])[d] - ent_w[e][d]|)
// b in [0,64), e in [0,100000), d in [0,128). All f32.
//
// Design: VALU-bound (2 lane-ops/elem, ~20.8us floor). GEMM-like tiling:
//  - block = 128 threads (2 waves), E_TILE=128 entities, all 64 batches.
//  - per-thread 8x8 (b x e) register tile, float4 over d -> 1 B LDS/elem.
//  - q[64][132] staged once per block (pad 132 -> q-read rows hit distinct banks).
//  - ent K-tiled 32 dims/step into [128][36] (pad 36 -> 8 distinct banks, rest broadcast).
//  - LDS 52.2 KB -> 3 blocks/CU, grid 782.

#define NUM_ENT 100000
#define NUM_REL 500
#define EMB_DIM 128
#define GAMMA_F 12.0f
#define BATCH 64

#define THREADS 128
#define E_TILE 128
#define TB 8
#define TE 8
#define K_TILE 32
#define Q_STRIDE 132  // 128 + 4 pad
#define E_STRIDE 36   // 32 + 4 pad

typedef float f32x4 __attribute__((ext_vector_type(4)));

__global__ __launch_bounds__(THREADS, 2) void transe_score_kernel(
    const int* __restrict__ sub, const int* __restrict__ rel,
    const float* __restrict__ ent_w, const float* __restrict__ rel_w,
    float* __restrict__ out)
{
    __shared__ float q_lds[BATCH * Q_STRIDE];   // 33792 B
    __shared__ float e_lds[E_TILE * E_STRIDE];  // 18432 B

    const int tid = threadIdx.x;
    const int e0 = blockIdx.x * E_TILE;

    // ---- Stage q = ent_w[sub[b]] + rel_w[rel[b]] (full 128 dims) ----
    for (int idx = tid * 4; idx < BATCH * EMB_DIM; idx += THREADS * 4) {
        int b = idx >> 7;       // idx/128
        int d = idx & 127;
        int s = sub[b];
        int r = rel[b];
        f32x4 a = *(const f32x4*)(ent_w + (size_t)s * EMB_DIM + d);
        f32x4 c = *(const f32x4*)(rel_w + (size_t)r * EMB_DIM + d);
        f32x4 qv = a + c;
        *(f32x4*)(q_lds + b * Q_STRIDE + d) = qv;
    }

    const int bq = tid & 7;   // 0..7  : batch group, b = bq + 8*i
    const int eq = tid >> 3;  // 0..15 : entity group, e = eq + 16*j

    float acc[TB][TE];
#pragma unroll
    for (int i = 0; i < TB; ++i)
#pragma unroll
        for (int j = 0; j < TE; ++j) acc[i][j] = 0.0f;

    for (int k0 = 0; k0 < EMB_DIM; k0 += K_TILE) {
        __syncthreads();  // protect e_lds from previous iter's readers; 1st iter: also orders q staging
        // ---- Stage ent K-slice: e_lds[row][dk] = ent_w[e0+row][k0+dk] ----
        for (int idx = tid * 4; idx < E_TILE * K_TILE; idx += THREADS * 4) {
            int row = idx >> 5;  // idx/32
            int dk = idx & 31;
            int e = e0 + row;
            if (e < NUM_ENT) {
                f32x4 v = *(const f32x4*)(ent_w + (size_t)e * EMB_DIM + k0 + dk);
                *(f32x4*)(e_lds + row * E_STRIDE + dk) = v;
            }
        }
        __syncthreads();

        // ---- Compute: acc[i][j] += sum over this K-slice of |q - e| ----
        for (int d4 = 0; d4 < K_TILE / 4; ++d4) {
            f32x4 qv[TB];
            f32x4 ev[TE];
#pragma unroll
            for (int i = 0; i < TB; ++i)
                qv[i] = *(const f32x4*)(q_lds + (bq + 8 * i) * Q_STRIDE + k0 + d4 * 4);
#pragma unroll
            for (int j = 0; j < TE; ++j)
                ev[j] = *(const f32x4*)(e_lds + (eq + 16 * j) * E_STRIDE + d4 * 4);
#pragma unroll
            for (int i = 0; i < TB; ++i) {
#pragma unroll
                for (int j = 0; j < TE; ++j) {
                    acc[i][j] += fabsf(qv[i].x - ev[j].x);
                    acc[i][j] += fabsf(qv[i].y - ev[j].y);
                    acc[i][j] += fabsf(qv[i].z - ev[j].z);
                    acc[i][j] += fabsf(qv[i].w - ev[j].w);
                }
            }
        }
    }

    // ---- Epilogue: sigmoid(GAMMA - dist), coalesced-ish scalar stores ----
#pragma unroll
    for (int i = 0; i < TB; ++i) {
        int b = bq + 8 * i;
#pragma unroll
        for (int j = 0; j < TE; ++j) {
            int e = e0 + eq + 16 * j;
            if (e < NUM_ENT) {
                float x = acc[i][j] - GAMMA_F;  // dist - gamma
                out[(size_t)b * NUM_ENT + e] = 1.0f / (1.0f + __expf(x));
            }
        }
    }
}

extern "C" void kernel_launch(void* const* d_in, const int* in_sizes, int n_in,
                              void* d_out, int out_size, void* d_ws, size_t ws_size,
                              hipStream_t stream) {
    const int* sub = (const int*)d_in[0];
    const int* rel = (const int*)d_in[1];
    const float* ent_w = (const float*)d_in[2];
    const float* rel_w = (const float*)d_in[3];
    float* out = (float*)d_out;

    dim3 grid((NUM_ENT + E_TILE - 1) / E_TILE);  // 782
    dim3 block(THREADS);
    transe_score_kernel<<<grid, block, 0, stream>>>(sub, rel, ent_w, rel_w, out);
}

// Round 2
// 78.319 us; speedup vs baseline: 1.6299x; 1.6299x over previous
//
#include <hip/hip_runtime.h>
#include <math.h>

// TransE: out[b,e] = sigmoid(12 - sum_d |(ent_w[sub[b]]+rel_w[rel[b]])[d] - ent_w[e][d]|)
// b in [0,64), e in [0,100000), d in [0,128). f32.
//
// Round-2 design (lane = batch):
//  - BATCH == 64 == wavefront. Lane l owns batch l; q[l][0..127] lives in 128 VGPRs.
//    -> the q operand costs ZERO LDS traffic (was 8 of 16 ds_reads per step).
//  - Each wave independently processes units of 4 entities. Unit rows staged into a
//    wave-PRIVATE LDS region with one wide coalesced load (64 lanes x 32B = 2KB),
//    then consumed as true-broadcast ds_read_b128 (single address -> conflict-free,
//    1 LDS instr per 8 VALU instr). No __syncthreads anywhere.
//  - Next unit's global loads issued before compute (latency hidden under 1024 VALU).
//  - Stores: per-lane f32x4 (4 entities); the 4 units of each 64B line map to the
//    4 waves of ONE block -> same XCD, L2 write-merge.
//  - 512 blocks x 256 thr = 2048 waves, all co-resident (2 blocks/CU, 2 waves/SIMD).

#define NUM_ENT 100000
#define NUM_REL 500
#define EMB_DIM 128
#define GAMMA_F 12.0f
#define BATCH 64

#define THREADS 256
#define WAVES_PER_BLOCK (THREADS / 64)
#define BLOCKS 512
#define TOTAL_WAVES (BLOCKS * WAVES_PER_BLOCK)  // 2048
#define UNIT 4                                   // entities per unit
#define NUM_UNITS (NUM_ENT / UNIT)               // 25000

typedef float f32x4 __attribute__((ext_vector_type(4)));

__global__ __launch_bounds__(THREADS, 2) void transe_score_kernel(
    const int* __restrict__ sub, const int* __restrict__ rel,
    const float* __restrict__ ent_w, const float* __restrict__ rel_w,
    float* __restrict__ out)
{
    __shared__ __align__(16) float elds[WAVES_PER_BLOCK][UNIT * EMB_DIM];  // 8 KB

    const int lane = threadIdx.x & 63;
    const int wv = threadIdx.x >> 6;
    const int gwv = blockIdx.x * WAVES_PER_BLOCK + wv;  // 0..2047

    // ---- q[lane][:] = ent_w[sub[lane]] + rel_w[rel[lane]] into 128 VGPRs ----
    const int s = sub[lane];
    const int r = rel[lane];
    const float* __restrict__ srow = ent_w + (size_t)s * EMB_DIM;
    const float* __restrict__ rrow = rel_w + (size_t)r * EMB_DIM;
    f32x4 q[EMB_DIM / 4];
#pragma unroll
    for (int c = 0; c < EMB_DIM / 4; ++c) {
        f32x4 a = *(const f32x4*)(srow + c * 4);
        f32x4 b = *(const f32x4*)(rrow + c * 4);
        q[c] = a + b;
    }

    float* __restrict__ myl = &elds[wv][0];
    float* __restrict__ orow = out + (size_t)lane * NUM_ENT;

    // ---- unit loop: grid-stride over 4-entity units ----
    int u = gwv;
    // prologue: load unit u stage regs (lane covers 8 consecutive floats)
    const float* __restrict__ src = ent_w + (size_t)u * (UNIT * EMB_DIM) + lane * 8;
    f32x4 t0 = *(const f32x4*)(src);
    f32x4 t1 = *(const f32x4*)(src + 4);

    while (u < NUM_UNITS) {
        // stage current unit into wave-private LDS
        *(f32x4*)(myl + lane * 8) = t0;
        *(f32x4*)(myl + lane * 8 + 4) = t1;

        // issue next unit's global loads (hidden under compute)
        const int un = u + TOTAL_WAVES;
        if (un < NUM_UNITS) {
            const float* __restrict__ nsrc = ent_w + (size_t)un * (UNIT * EMB_DIM) + lane * 8;
            t0 = *(const f32x4*)(nsrc);
            t1 = *(const f32x4*)(nsrc + 4);
        }

        // compute 4 entities: broadcast ds_read_b128 + 8 VALU per 4 dims
        f32x4 resv;
#pragma unroll
        for (int e = 0; e < UNIT; ++e) {
            const float* __restrict__ ep = myl + e * EMB_DIM;
            float a0 = 0.0f, a1 = 0.0f, a2 = 0.0f, a3 = 0.0f;
#pragma unroll
            for (int c = 0; c < EMB_DIM / 4; ++c) {
                f32x4 ev = *(const f32x4*)(ep + c * 4);
                a0 += fabsf(q[c][0] - ev[0]);
                a1 += fabsf(q[c][1] - ev[1]);
                a2 += fabsf(q[c][2] - ev[2]);
                a3 += fabsf(q[c][3] - ev[3]);
            }
            float dist = (a0 + a1) + (a2 + a3);
            resv[e] = 1.0f / (1.0f + __expf(dist - GAMMA_F));
        }

        // store 4 entities (16B per lane; 4 units/line all in this block)
        *(f32x4*)(orow + (size_t)u * UNIT) = resv;

        u = un;
    }
}

extern "C" void kernel_launch(void* const* d_in, const int* in_sizes, int n_in,
                              void* d_out, int out_size, void* d_ws, size_t ws_size,
                              hipStream_t stream) {
    const int* sub = (const int*)d_in[0];
    const int* rel = (const int*)d_in[1];
    const float* ent_w = (const float*)d_in[2];
    const float* rel_w = (const float*)d_in[3];
    float* out = (float*)d_out;

    transe_score_kernel<<<dim3(BLOCKS), dim3(THREADS), 0, stream>>>(sub, rel, ent_w, rel_w, out);
}